// Round 1
// baseline (15562.390 us; speedup 1.0000x reference)
//
#include <hip/hip_runtime.h>

#define TT 1024
#define BB 64
#define II 64
#define HH 256
#define DD 3
#define NEG 0.01f

__device__ __forceinline__ float lrelu(float z) { return z >= 0.f ? z : NEG * z; }

// ws layout (floats):
//   WT_hh: [3][256][256]  at offset 0            (k-major, diag zeroed)
//   WT_ff: [2][256][256]  at offset 196608
//   WT_in: [3][64][256]   at offset 327680
//   total 376832 floats = 1.4375 MB

__global__ void prep_transpose(const float* __restrict__ Whh,
                               const float* __restrict__ Wff,
                               const float* __restrict__ Win,
                               float* __restrict__ ws) {
    int idx = blockIdx.x * blockDim.x + threadIdx.x;
    const int N1 = DD * HH * HH;       // 196608
    const int N2 = 2 * HH * HH;        // 131072
    const int N3 = DD * II * HH;       // 49152
    if (idx < N1) {
        int h = idx & (HH - 1);
        int k = (idx >> 8) & (HH - 1);
        int d = idx >> 16;
        float v = Whh[(d * HH + h) * HH + k];
        ws[idx] = (h == k) ? 0.f : v;
    } else if (idx < N1 + N2) {
        int j = idx - N1;
        int h = j & (HH - 1);
        int k = (j >> 8) & (HH - 1);
        int e = j >> 16;
        ws[idx] = Wff[(e * HH + h) * HH + k];
    } else if (idx < N1 + N2 + N3) {
        int j = idx - N1 - N2;
        int h = j & (HH - 1);
        int k = (j >> 8) & (II - 1);
        int d = j >> 14;               // II*HH = 16384
        ws[idx] = Win[(d * HH + h) * II + k];
    }
}

__device__ __forceinline__ float dot256(const float* __restrict__ w,
                                        const float* __restrict__ hvec, int tid) {
    float a0 = 0.f, a1 = 0.f, a2 = 0.f, a3 = 0.f;
#pragma unroll 8
    for (int k = 0; k < HH; k += 4) {
        a0 += hvec[k + 0] * w[(k + 0) * HH + tid];
        a1 += hvec[k + 1] * w[(k + 1) * HH + tid];
        a2 += hvec[k + 2] * w[(k + 2) * HH + tid];
        a3 += hvec[k + 3] * w[(k + 3) * HH + tid];
    }
    return (a0 + a1) + (a2 + a3);
}

__device__ __forceinline__ float dot64(const float* __restrict__ w,
                                       const float* __restrict__ xvec, int tid) {
    float a0 = 0.f, a1 = 0.f, a2 = 0.f, a3 = 0.f;
#pragma unroll 4
    for (int k = 0; k < II; k += 4) {
        a0 += xvec[k + 0] * w[(k + 0) * HH + tid];
        a1 += xvec[k + 1] * w[(k + 1) * HH + tid];
        a2 += xvec[k + 2] * w[(k + 2) * HH + tid];
        a3 += xvec[k + 3] * w[(k + 3) * HH + tid];
    }
    return (a0 + a1) + (a2 + a3);
}

__global__ __launch_bounds__(256, 1) void rnn_persist(
    const float* __restrict__ data, const float* __restrict__ h0,
    const float* __restrict__ b_in, const float* __restrict__ b_hh,
    const float* __restrict__ b_ff, const float* __restrict__ taus,
    const float* __restrict__ W_fc, const float* __restrict__ b_fc,
    const float* __restrict__ ws, float* __restrict__ out) {
    const int b = blockIdx.x;     // batch element
    const int tid = threadIdx.x;  // hidden index

    const float* WT_hh = ws;
    const float* WT_ff = ws + DD * HH * HH;
    const float* WT_in = ws + DD * HH * HH + 2 * HH * HH;

    __shared__ float hs[DD][HH];
    __shared__ float xt[II];

    float dec[DD], itau[DD], bhh[DD], bin[DD], bff[2];
#pragma unroll
    for (int d = 0; d < DD; ++d) {
        float tc = taus[d * HH + tid];
        tc = tc < 1.f ? 1.f : tc;
        itau[d] = 1.f / tc;
        dec[d] = 1.f - itau[d];
        bhh[d] = b_hh[d * HH + tid];
        bin[d] = b_in[d * HH + tid];
        hs[d][tid] = h0[(d * BB + b) * HH + tid];
    }
    bff[0] = b_ff[tid];
    bff[1] = b_ff[HH + tid];
    __syncthreads();

    for (int t = 0; t < TT; ++t) {
        if (tid < II) xt[tid] = data[(t * BB + b) * II + tid];
        __syncthreads();

        // ---- layer 0 ----
        {
            float acc = bin[0] + bhh[0];
            acc += dot64(WT_in + 0 * II * HH, xt, tid);
            acc += dot256(WT_hh + 0 * HH * HH, hs[0], tid);
            float nh = dec[0] * hs[0][tid] + lrelu(acc) * itau[0];
            __syncthreads();
            hs[0][tid] = nh;
            __syncthreads();
        }
        // ---- layer 1 ----
        {
            float ff = bff[0] + dot256(WT_ff + 0 * HH * HH, hs[0], tid);
            float acc = bin[1] + bhh[1] + lrelu(ff);
            acc += dot64(WT_in + 1 * II * HH, xt, tid);
            acc += dot256(WT_hh + 1 * HH * HH, hs[1], tid);
            float nh = dec[1] * hs[1][tid] + lrelu(acc) * itau[1];
            __syncthreads();
            hs[1][tid] = nh;
            __syncthreads();
        }
        // ---- layer 2 ----
        {
            float ff = bff[1] + dot256(WT_ff + 1 * HH * HH, hs[1], tid);
            float acc = bin[2] + bhh[2] + lrelu(ff);
            acc += dot64(WT_in + 2 * II * HH, xt, tid);
            acc += dot256(WT_hh + 2 * HH * HH, hs[2], tid);
            float nh = dec[2] * hs[2][tid] + lrelu(acc) * itau[2];
            __syncthreads();
            hs[2][tid] = nh;
            __syncthreads();
        }
    }

    // ---- outputs ----
#pragma unroll
    for (int d = 0; d < DD; ++d) out[(d * BB + b) * HH + tid] = hs[d][tid];

    if (tid < DD * 2) {
        int dd = tid >> 1, c = tid & 1;
        float a = b_fc[dd * 2 + c];
#pragma unroll 8
        for (int k = 0; k < HH; ++k) a += hs[DD - 1][k] * W_fc[(dd * 2 + c) * HH + k];
        out[DD * BB * HH + (dd * BB + b) * 2 + c] = a;
    }
}

extern "C" void kernel_launch(void* const* d_in, const int* in_sizes, int n_in,
                              void* d_out, int out_size, void* d_ws, size_t ws_size,
                              hipStream_t stream) {
    const float* data = (const float*)d_in[0];
    const float* h0   = (const float*)d_in[1];
    const float* W_in = (const float*)d_in[2];
    const float* b_in = (const float*)d_in[3];
    const float* W_hh = (const float*)d_in[4];
    const float* b_hh = (const float*)d_in[5];
    const float* W_ff = (const float*)d_in[6];
    const float* b_ff = (const float*)d_in[7];
    const float* taus = (const float*)d_in[8];
    const float* W_fc = (const float*)d_in[9];
    const float* b_fc = (const float*)d_in[10];
    float* out = (float*)d_out;
    float* ws  = (float*)d_ws;

    const int total = DD * HH * HH + 2 * HH * HH + DD * II * HH;  // 376832
    prep_transpose<<<(total + 255) / 256, 256, 0, stream>>>(W_hh, W_ff, W_in, ws);
    rnn_persist<<<BB, HH, 0, stream>>>(data, h0, b_in, b_hh, b_ff, taus,
                                       W_fc, b_fc, ws, out);
}